// Round 9
// baseline (773.973 us; speedup 1.0000x reference)
//
#include <hip/hip_runtime.h>
#include <hip/hip_bf16.h>
#include <cmath>

#define NNODES 100000
#define NEDGES 1600000
#define SCAN_B 1024

typedef __attribute__((ext_vector_type(8))) short bf16x8;
typedef __attribute__((ext_vector_type(4))) float f32x4;

// RNE fp32 -> bf16 (finite inputs)
__device__ __forceinline__ unsigned short f2bf(float f) {
    unsigned u = __builtin_bit_cast(unsigned, f);
    unsigned r = (u + 0x7fffu + ((u >> 16) & 1u)) >> 16;
    return (unsigned short)r;
}
__device__ __forceinline__ float bflo(unsigned v) {
    return __builtin_bit_cast(float, v << 16);
}
__device__ __forceinline__ float bfhi(unsigned v) {
    return __builtin_bit_cast(float, v & 0xffff0000u);
}

// ---------------- CSR build ----------------

__global__ void zero_deg(int* __restrict__ deg, int n) {
    int i = blockIdx.x * 256 + threadIdx.x;
    if (i < n) deg[i] = 0;
}

// XCD-partitioned degree count (verified R4): atomics stay in one XCD's L2.
__global__ __launch_bounds__(256) void count_deg_xcd(const int* __restrict__ dst,
                                                     int* __restrict__ deg, int E) {
    int g = blockIdx.x & 7;
    int sub = blockIdx.x >> 3;
    int nsub = gridDim.x >> 3;
    int lo = g * (NNODES / 8), hi = lo + (NNODES / 8);
    for (int e = sub * 256 + threadIdx.x; e < E; e += nsub * 256) {
        int d = dst[e];
        if (d >= lo && d < hi) atomicAdd(&deg[d], 1);
    }
}

__global__ void calc_dinv(const int* __restrict__ deg, float* __restrict__ dinv, int n) {
    int i = blockIdx.x * 256 + threadIdx.x;
    if (i < n) dinv[i] = rsqrtf(1.0f + (float)deg[i]);   // +1 self-loop
}

__global__ __launch_bounds__(SCAN_B) void scan_block(const int* __restrict__ deg,
                                                     int* __restrict__ pos,
                                                     int* __restrict__ bsums, int n) {
    __shared__ int s[SCAN_B];
    int tid = threadIdx.x;
    int gid = blockIdx.x * SCAN_B + tid;
    int v = (gid < n) ? deg[gid] : 0;
    s[tid] = v;
    __syncthreads();
    for (int off = 1; off < SCAN_B; off <<= 1) {
        int t = (tid >= off) ? s[tid - off] : 0;
        __syncthreads();
        s[tid] += t;
        __syncthreads();
    }
    if (gid < n) pos[gid] = s[tid] - v;          // exclusive
    if (tid == SCAN_B - 1) bsums[blockIdx.x] = s[tid];
}

__global__ __launch_bounds__(128) void scan_sums(int* __restrict__ bsums, int nb) {
    __shared__ int s[128];
    int tid = threadIdx.x;
    int v = (tid < nb) ? bsums[tid] : 0;
    s[tid] = v;
    __syncthreads();
    for (int off = 1; off < 128; off <<= 1) {
        int t = (tid >= off) ? s[tid - off] : 0;
        __syncthreads();
        s[tid] += t;
        __syncthreads();
    }
    if (tid < nb) bsums[tid] = s[tid] - v;       // exclusive
}

__global__ __launch_bounds__(SCAN_B) void add_off(int* __restrict__ pos,
                                                  const int* __restrict__ bsums, int n) {
    int gid = blockIdx.x * SCAN_B + threadIdx.x;
    if (gid < n) pos[gid] += bsums[blockIdx.x];
}

// XCD-partitioned CSR fill (verified R4).
__global__ __launch_bounds__(256) void csr_fill_xcd(const int* __restrict__ src,
                                                    const int* __restrict__ dst,
                                                    int* __restrict__ pos,
                                                    int* __restrict__ csr_src, int E) {
    int g = blockIdx.x & 7;
    int sub = blockIdx.x >> 3;
    int nsub = gridDim.x >> 3;
    int lo = g * (NNODES / 8), hi = lo + (NNODES / 8);
    for (int e = sub * 256 + threadIdx.x; e < E; e += nsub * 256) {
        int d = dst[e];
        if (d >= lo && d < hi) {
            int slot = atomicAdd(&pos[d], 1);
            csr_src[slot] = src[e];
        }
    }
}

// ---------------- weight convert: fragment-contiguous layouts ----------------
// W1f: for k-tile t (16), col-group j (8), lane l (64): 8 bf16 at
//   W1f[((t*8+j)*64+l)*8 + jj] = bf16(W1[k][n]), k = t*32+(l>>4)*8+jj, n = j*16+(l&15)
// -> a wave's bfr[j] load is one contiguous 1KB segment (L2-resident, reused by all blocks).

__global__ __launch_bounds__(256) void conv_w1f(const float* __restrict__ W1,
                                                unsigned short* __restrict__ W1f) {
    int idx = blockIdx.x * 256 + threadIdx.x;    // 16*8*64 = 8192
    if (idx >= 8192) return;
    int t = idx >> 9;
    int rest = idx & 511;
    int j = rest >> 6;
    int l = rest & 63;
    int n = j * 16 + (l & 15);
    int kb = t * 32 + (l >> 4) * 8;
    bf16x8 o;
    #pragma unroll
    for (int jj = 0; jj < 8; jj++) {
        int k = kb + jj;
        o[jj] = (k < 500) ? (short)f2bf(W1[k * 128 + n]) : (short)0;
    }
    *(bf16x8*)(W1f + (size_t)idx * 8) = o;
}

// W2f: k-tiles t (4), col-groups j (4), lanes l (64); k = t*32+(l>>4)*8+jj, n = j*16+(l&15)
__global__ __launch_bounds__(256) void conv_w2f(const float* __restrict__ W2,
                                                unsigned short* __restrict__ W2f) {
    int idx = blockIdx.x * 256 + threadIdx.x;    // 4*4*64 = 1024
    if (idx >= 1024) return;
    int t = idx >> 8;
    int rest = idx & 255;
    int j = rest >> 6;
    int l = rest & 63;
    int n = j * 16 + (l & 15);
    int kb = t * 32 + (l >> 4) * 8;
    bf16x8 o;
    #pragma unroll
    for (int jj = 0; jj < 8; jj++)
        o[jj] = (short)f2bf(W2[(kb + jj) * 64 + n]);
    *(bf16x8*)(W2f + (size_t)idx * 8) = o;
}

// ---------------- layer-1 MFMA GEMM: h1'[M,128](bf16) = dinv .* (x @ W1) ----------
// BM=64, barrier-free, LDS-free, depth-1 register prefetch FORCED live via
// sched_barrier(0): loads of tile t+1 are pinned above tile t's MFMAs, so
// their s_waitcnt lands after the MFMA block. Main loop (t=0..14) is
// branchless (max element q*8+448+7 = 479 < 500); t=15 tail in epilogue.

__global__ __launch_bounds__(256) void gemm1_mfma(
    const float* __restrict__ x, const unsigned short* __restrict__ W1f,
    const float* __restrict__ dinv, unsigned short* __restrict__ C, int M)
{
    const int tid = threadIdx.x;
    const int w = tid >> 6;
    const int l = tid & 63;
    const int lm = l & 15;
    const int q = l >> 4;
    const int row0 = blockIdx.x * 64;

    int r = row0 + w * 16 + lm;
    if (r >= M) r = M - 1;
    const float* abase = x + (size_t)r * 500 + q * 8;
    const unsigned short* bbase = W1f + (size_t)l * 8;

    f32x4 acc[8];
    #pragma unroll
    for (int j = 0; j < 8; j++) acc[j] = (f32x4){0.f, 0.f, 0.f, 0.f};

    bf16x8 a0, a1, b0[8], b1[8];

#define LA(dst, k0) do {                                                   \
        float4 _u = *(const float4*)(abase + (k0));                        \
        float4 _v = *(const float4*)(abase + (k0) + 4);                    \
        bf16x8 _o;                                                         \
        _o[0] = f2bf(_u.x); _o[1] = f2bf(_u.y);                            \
        _o[2] = f2bf(_u.z); _o[3] = f2bf(_u.w);                            \
        _o[4] = f2bf(_v.x); _o[5] = f2bf(_v.y);                            \
        _o[6] = f2bf(_v.z); _o[7] = f2bf(_v.w);                            \
        dst = _o;                                                          \
    } while (0)

#define LB(dst, t) do {                                                    \
        _Pragma("unroll")                                                  \
        for (int _j = 0; _j < 8; _j++)                                     \
            dst[_j] = *(const bf16x8*)(bbase + (size_t)((t) * 8 + _j) * 512); \
    } while (0)

#define MF(aa, bb) do {                                                    \
        _Pragma("unroll")                                                  \
        for (int _j = 0; _j < 8; _j++)                                     \
            acc[_j] = __builtin_amdgcn_mfma_f32_16x16x32_bf16(aa, bb[_j], acc[_j], 0, 0, 0); \
    } while (0)

    // preload tile 0 -> set0
    LA(a0, 0); LB(b0, 0);

    for (int tt = 0; tt < 7; ++tt) {            // pairs (0,1) .. (12,13)
        const int t0 = 2 * tt, t1 = t0 + 1;
        LA(a1, t1 * 32); LB(b1, t1);            // prefetch t1 -> set1
        __builtin_amdgcn_sched_barrier(0);      // pin: loads above, MFMAs below
        MF(a0, b0);                             // compute t0
        LA(a0, (t0 + 2) * 32); LB(b0, t0 + 2);  // prefetch t0+2 (<=14) -> set0
        __builtin_amdgcn_sched_barrier(0);
        MF(a1, b1);                             // compute t1
    }
    // set0 now holds tile 14; tail tile 15 (guarded per element) -> set1
    {
        bf16x8 o;
        #pragma unroll
        for (int jj = 0; jj < 8; jj++) {
            int k = 480 + q * 8 + jj;
            o[jj] = (k < 500) ? (short)f2bf(abase[480 + jj]) : (short)0;
        }
        a1 = o;
        LB(b1, 15);
    }
    __builtin_amdgcn_sched_barrier(0);
    MF(a0, b0);                                 // tile 14
    MF(a1, b1);                                 // tile 15

#undef LA
#undef LB
#undef MF

    // C/D layout: col = j*16 + lm, row = q*4 + reg (+ w*16); pre-scale by dinv[row]
    #pragma unroll
    for (int reg = 0; reg < 4; reg++) {
        int grow = row0 + w * 16 + q * 4 + reg;
        if (grow < M) {
            float d = dinv[grow];
            #pragma unroll
            for (int j = 0; j < 8; j++)
                C[(size_t)grow * 128 + j * 16 + lm] = f2bf(d * acc[j][reg]);
        }
    }
}

// ---------------- layer-2 MFMA GEMM: h2'[M,64](bf16) = dinv .* (a1 @ W2) ----------
// Barrier-free register-direct (verified R7).

__global__ __launch_bounds__(256) void gemm2_mfma(
    const unsigned short* __restrict__ A, const unsigned short* __restrict__ W2f,
    const float* __restrict__ dinv, unsigned short* __restrict__ C, int M)
{
    const int tid = threadIdx.x;
    const int w = tid >> 6;
    const int l = tid & 63;
    const int lm = l & 15;
    const int q = l >> 4;
    const int row0 = blockIdx.x * 128;

    const unsigned short* abase[2];
    #pragma unroll
    for (int i = 0; i < 2; i++) {
        int r = row0 + w * 32 + i * 16 + lm;
        if (r >= M) r = M - 1;
        abase[i] = A + (size_t)r * 128 + q * 8;
    }

    f32x4 acc[2][4];
    #pragma unroll
    for (int i = 0; i < 2; i++)
        #pragma unroll
        for (int j = 0; j < 4; j++) acc[i][j] = (f32x4){0.f, 0.f, 0.f, 0.f};

    for (int t = 0; t < 4; ++t) {
        const int k0 = t * 32;
        bf16x8 af[2];
        #pragma unroll
        for (int i = 0; i < 2; i++)
            af[i] = *(const bf16x8*)(abase[i] + k0);
        bf16x8 bfr[4];
        #pragma unroll
        for (int j = 0; j < 4; j++)
            bfr[j] = *(const bf16x8*)(W2f + (((size_t)t * 4 + j) * 64 + l) * 8);
        #pragma unroll
        for (int i = 0; i < 2; i++)
            #pragma unroll
            for (int j = 0; j < 4; j++)
                acc[i][j] = __builtin_amdgcn_mfma_f32_16x16x32_bf16(af[i], bfr[j], acc[i][j], 0, 0, 0);
    }

    #pragma unroll
    for (int i = 0; i < 2; i++) {
        #pragma unroll
        for (int reg = 0; reg < 4; reg++) {
            int grow = row0 + w * 32 + i * 16 + q * 4 + reg;
            if (grow < M) {
                float d = dinv[grow];
                #pragma unroll
                for (int j = 0; j < 4; j++)
                    C[(size_t)grow * 64 + j * 16 + lm] = f2bf(d * acc[i][j][reg]);
            }
        }
    }
}

// ---------------- layer-3 GEMM: h3'[M,40](fp32) = dinv .* (relu(A+b2) @ W4) ----------------

__global__ __launch_bounds__(256) void gemm_n40(
    const float* __restrict__ A, const float* __restrict__ W,
    const float* __restrict__ bias, const float* __restrict__ dinv,
    float* __restrict__ C, int M)
{
    __shared__ float sA[32][65];
    __shared__ float sW[64][40];
    const int row0 = blockIdx.x * 32;
    for (int idx = threadIdx.x; idx < 64 * 40; idx += 256)
        sW[idx / 40][idx % 40] = W[idx];
    for (int idx = threadIdx.x; idx < 32 * 64; idx += 256) {
        int r = idx >> 6, k = idx & 63;
        int row = row0 + r;
        float v = 0.0f;
        if (row < M) v = fmaxf(A[(long)row * 64 + k] + bias[k], 0.0f);
        sA[r][k] = v;
    }
    __syncthreads();
    float acc[5] = {0, 0, 0, 0, 0};
    int rr[5], cc[5];
    #pragma unroll
    for (int j = 0; j < 5; j++) {
        int o = threadIdx.x + 256 * j;
        rr[j] = o / 40; cc[j] = o % 40;
    }
    for (int k = 0; k < 64; k++) {
        #pragma unroll
        for (int j = 0; j < 5; j++) acc[j] += sA[rr[j]][k] * sW[k][cc[j]];
    }
    #pragma unroll
    for (int j = 0; j < 5; j++) {
        int row = row0 + rr[j];
        if (row < M) C[(long)row * 40 + cc[j]] = dinv[row] * acc[j];
    }
}

// ---------------- CSR gather over pre-scaled bf16 h': out[i] = di*(h'[i] + sum h'[s]) ----
// optional fused +bias,relu,->bf16 epilogue

template<int F, bool OBF16>
__global__ __launch_bounds__(256) void gather_bf(
    const unsigned short* __restrict__ h, const float* __restrict__ dinv,
    const int* __restrict__ pos, const int* __restrict__ csr_src,
    void* __restrict__ outv, const float* __restrict__ bias, int n)
{
    constexpr int P = F / 2;
    unsigned t = blockIdx.x * 256u + threadIdx.x;
    unsigned node = t / P;
    unsigned p = t - node * P;
    if (node >= (unsigned)n) return;
    int e0 = node ? pos[node - 1] : 0;
    int e1 = pos[node];
    float di = dinv[node];
    unsigned sv = *(const unsigned*)(h + (size_t)node * F + 2 * p);
    float a0 = bflo(sv);
    float a1 = bfhi(sv);
    int j = e0;
    for (; j + 4 <= e1; j += 4) {
        int s0 = csr_src[j], s1 = csr_src[j + 1], s2 = csr_src[j + 2], s3 = csr_src[j + 3];
        unsigned v0 = *(const unsigned*)(h + (size_t)s0 * F + 2 * p);
        unsigned v1 = *(const unsigned*)(h + (size_t)s1 * F + 2 * p);
        unsigned v2 = *(const unsigned*)(h + (size_t)s2 * F + 2 * p);
        unsigned v3 = *(const unsigned*)(h + (size_t)s3 * F + 2 * p);
        a0 += bflo(v0) + bflo(v1) + bflo(v2) + bflo(v3);
        a1 += bfhi(v0) + bfhi(v1) + bfhi(v2) + bfhi(v3);
    }
    for (; j < e1; j++) {
        int s = csr_src[j];
        unsigned v = *(const unsigned*)(h + (size_t)s * F + 2 * p);
        a0 += bflo(v);
        a1 += bfhi(v);
    }
    a0 *= di; a1 *= di;
    if constexpr (OBF16) {
        a0 = fmaxf(a0 + bias[2 * p], 0.0f);
        a1 = fmaxf(a1 + bias[2 * p + 1], 0.0f);
        ((unsigned*)outv)[(size_t)node * P + p] =
            ((unsigned)f2bf(a1) << 16) | (unsigned)f2bf(a0);
    } else {
        float2 r; r.x = a0; r.y = a1;
        ((float2*)outv)[(size_t)node * P + p] = r;
    }
}

// ---------------- fp32 CSR gather over pre-scaled h' (layer 3, F=40) ----------------

template<int F>
__global__ __launch_bounds__(256) void gather_agg(
    const float* __restrict__ h, const float* __restrict__ dinv,
    const int* __restrict__ pos, const int* __restrict__ csr_src,
    float* __restrict__ out, int n)
{
    unsigned t = blockIdx.x * 256u + threadIdx.x;
    unsigned node = t / F;
    unsigned c = t - node * F;
    if (node >= (unsigned)n) return;
    int e0 = node ? pos[node - 1] : 0;
    int e1 = pos[node];
    float di = dinv[node];
    float acc = h[(size_t)node * F + c];
    int j = e0;
    for (; j + 4 <= e1; j += 4) {
        int s0 = csr_src[j], s1 = csr_src[j + 1], s2 = csr_src[j + 2], s3 = csr_src[j + 3];
        float v0 = h[(size_t)s0 * F + c];
        float v1 = h[(size_t)s1 * F + c];
        float v2 = h[(size_t)s2 * F + c];
        float v3 = h[(size_t)s3 * F + c];
        acc += v0 + v1 + v2 + v3;
    }
    for (; j < e1; j++) {
        int s = csr_src[j];
        acc += h[(size_t)s * F + c];
    }
    out[(size_t)node * F + c] = di * acc;
}

// ---------------- log_softmax over rows of 40 (one wave per row), in-place safe ----------------

__global__ __launch_bounds__(256) void logsoftmax40(const float* __restrict__ h,
                                                    const float* __restrict__ bias,
                                                    float* __restrict__ out, int n) {
    int wave = (blockIdx.x * 256 + threadIdx.x) >> 6;
    int lane = threadIdx.x & 63;
    if (wave >= n) return;
    float x = 0.0f, v = -INFINITY;
    if (lane < 40) { x = h[(long)wave * 40 + lane] + bias[lane]; v = x; }
    #pragma unroll
    for (int off = 32; off; off >>= 1) v = fmaxf(v, __shfl_xor(v, off, 64));
    float ex = (lane < 40) ? expf(x - v) : 0.0f;
    float s = ex;
    #pragma unroll
    for (int off = 32; off; off >>= 1) s += __shfl_xor(s, off, 64);
    if (lane < 40) out[(long)wave * 40 + lane] = x - v - logf(s);
}

// ---------------- launch ----------------

extern "C" void kernel_launch(void* const* d_in, const int* in_sizes, int n_in,
                              void* d_out, int out_size, void* d_ws, size_t ws_size,
                              hipStream_t stream) {
    const float* x  = (const float*)d_in[0];
    const int*   ei = (const int*)d_in[1];
    const float* W1 = (const float*)d_in[2];
    const float* b1 = (const float*)d_in[3];
    const float* W2 = (const float*)d_in[4];
    const float* b2 = (const float*)d_in[5];
    const float* W4 = (const float*)d_in[6];
    const float* b4 = (const float*)d_in[7];
    float* out = (float*)d_out;
    float* ws  = (float*)d_ws;

    const int N = NNODES, E = NEDGES;
    const int* src = ei;
    const int* dst = ei + E;

    // workspace layout (float offsets), with overlay reuse (~85 MB total):
    float*          dinv    = ws;                              // 100k
    int*            deg     = (int*)(ws + 100000);
    int*            pos     = (int*)(ws + 200000);
    int*            bsums   = (int*)(ws + 300000);
    int*            csr_src = (int*)(ws + 300200);             // 1.6M ints
    unsigned short* W1f     = (unsigned short*)(ws + 1900200); // 65536 shorts
    unsigned short* W2f     = (unsigned short*)(ws + 1933000); // 8192 shorts
    // region R1: h1' bf16 [N][128]; later h2' bf16 [N][64]
    unsigned short* h1      = (unsigned short*)(ws + 1937100);
    unsigned short* h2      = (unsigned short*)(ws + 1937100);
    // region R2: a1 bf16 [N][128]; later h3' fp32 [N][40]
    unsigned short* a1      = (unsigned short*)(ws + 8337100);
    float*          h3      = ws + 8337100;
    // region R3: a2 fp32 [N][64]
    float*          a2      = ws + 14737100;
    float*          a3      = out;

    const int nscan = (N + SCAN_B - 1) / SCAN_B;

    // ---- CSR build + norm ----
    zero_deg<<<(N + 255) / 256, 256, 0, stream>>>(deg, N);
    count_deg_xcd<<<1024, 256, 0, stream>>>(dst, deg, E);
    calc_dinv<<<(N + 255) / 256, 256, 0, stream>>>(deg, dinv, N);
    scan_block<<<nscan, SCAN_B, 0, stream>>>(deg, pos, bsums, N);
    scan_sums<<<1, 128, 0, stream>>>(bsums, nscan);
    add_off<<<nscan, SCAN_B, 0, stream>>>(pos, bsums, N);
    csr_fill_xcd<<<1024, 256, 0, stream>>>(src, dst, pos, csr_src, E);

    // ---- weights convert (fragment layouts) ----
    conv_w1f<<<32, 256, 0, stream>>>(W1, W1f);
    conv_w2f<<<4, 256, 0, stream>>>(W2, W2f);

    // ---- layer 1: h1' = dinv.*(x @ W1) ; a1(bf16) = relu(di*(h1'[i]+sum h1'[s]) + b1) ----
    gemm1_mfma<<<(N + 63) / 64, 256, 0, stream>>>(x, W1f, dinv, h1, N);
    {
        unsigned tot = (unsigned)N * 64u;
        gather_bf<128, true><<<(tot + 255) / 256, 256, 0, stream>>>(h1, dinv, pos, csr_src, a1, b1, N);
    }

    // ---- layer 2: h2' = dinv.*(a1 @ W2) ; a2(fp32) = di*(h2'[i]+sum h2'[s]) ----
    gemm2_mfma<<<(N + 127) / 128, 256, 0, stream>>>(a1, W2f, dinv, h2, N);
    {
        unsigned tot = (unsigned)N * 32u;
        gather_bf<64, false><<<(tot + 255) / 256, 256, 0, stream>>>(h2, dinv, pos, csr_src, a2, nullptr, N);
    }

    // ---- layer 3: h3' = dinv.*(relu(a2+b2) @ W4) ; a3 = di*(h3'[i]+sum h3'[s]) ----
    gemm_n40<<<(N + 31) / 32, 256, 0, stream>>>(a2, W4, b2, dinv, h3, N);
    {
        unsigned tot = (unsigned)N * 40u;
        gather_agg<40><<<(tot + 255) / 256, 256, 0, stream>>>(h3, dinv, pos, csr_src, a3, N);
    }

    // ---- log_softmax(a3 + b4) in place ----
    logsoftmax40<<<(N * 64 + 255) / 256, 256, 0, stream>>>(a3, b4, out, N);
}

// Round 10
// 757.423 us; speedup vs baseline: 1.0219x; 1.0219x over previous
//
#include <hip/hip_runtime.h>
#include <hip/hip_bf16.h>
#include <cmath>

#define NNODES 100000
#define NEDGES 1600000
#define SCAN_B 1024

typedef __attribute__((ext_vector_type(8))) short bf16x8;
typedef __attribute__((ext_vector_type(4))) float f32x4;

// RNE fp32 -> bf16 (finite inputs)
__device__ __forceinline__ unsigned short f2bf(float f) {
    unsigned u = __builtin_bit_cast(unsigned, f);
    unsigned r = (u + 0x7fffu + ((u >> 16) & 1u)) >> 16;
    return (unsigned short)r;
}
__device__ __forceinline__ float bflo(unsigned v) {
    return __builtin_bit_cast(float, v << 16);
}
__device__ __forceinline__ float bfhi(unsigned v) {
    return __builtin_bit_cast(float, v & 0xffff0000u);
}

// async global->LDS DMA, 16B per lane; LDS dest = wave-uniform base + lane*16
__device__ __forceinline__ void gload16(const void* g, void* l) {
    __builtin_amdgcn_global_load_lds(
        (const __attribute__((address_space(1))) unsigned int*)g,
        (__attribute__((address_space(3))) unsigned int*)l, 16, 0, 0);
}

// ---------------- CSR build ----------------

__global__ void zero_deg(int* __restrict__ deg, int n) {
    int i = blockIdx.x * 256 + threadIdx.x;
    if (i < n) deg[i] = 0;
}

// XCD-partitioned degree count (verified R4): atomics stay in one XCD's L2.
__global__ __launch_bounds__(256) void count_deg_xcd(const int* __restrict__ dst,
                                                     int* __restrict__ deg, int E) {
    int g = blockIdx.x & 7;
    int sub = blockIdx.x >> 3;
    int nsub = gridDim.x >> 3;
    int lo = g * (NNODES / 8), hi = lo + (NNODES / 8);
    for (int e = sub * 256 + threadIdx.x; e < E; e += nsub * 256) {
        int d = dst[e];
        if (d >= lo && d < hi) atomicAdd(&deg[d], 1);
    }
}

__global__ void calc_dinv(const int* __restrict__ deg, float* __restrict__ dinv, int n) {
    int i = blockIdx.x * 256 + threadIdx.x;
    if (i < n) dinv[i] = rsqrtf(1.0f + (float)deg[i]);   // +1 self-loop
}

__global__ __launch_bounds__(SCAN_B) void scan_block(const int* __restrict__ deg,
                                                     int* __restrict__ pos,
                                                     int* __restrict__ bsums, int n) {
    __shared__ int s[SCAN_B];
    int tid = threadIdx.x;
    int gid = blockIdx.x * SCAN_B + tid;
    int v = (gid < n) ? deg[gid] : 0;
    s[tid] = v;
    __syncthreads();
    for (int off = 1; off < SCAN_B; off <<= 1) {
        int t = (tid >= off) ? s[tid - off] : 0;
        __syncthreads();
        s[tid] += t;
        __syncthreads();
    }
    if (gid < n) pos[gid] = s[tid] - v;          // exclusive
    if (tid == SCAN_B - 1) bsums[blockIdx.x] = s[tid];
}

__global__ __launch_bounds__(128) void scan_sums(int* __restrict__ bsums, int nb) {
    __shared__ int s[128];
    int tid = threadIdx.x;
    int v = (tid < nb) ? bsums[tid] : 0;
    s[tid] = v;
    __syncthreads();
    for (int off = 1; off < 128; off <<= 1) {
        int t = (tid >= off) ? s[tid - off] : 0;
        __syncthreads();
        s[tid] += t;
        __syncthreads();
    }
    if (tid < nb) bsums[tid] = s[tid] - v;       // exclusive
}

__global__ __launch_bounds__(SCAN_B) void add_off(int* __restrict__ pos,
                                                  const int* __restrict__ bsums, int n) {
    int gid = blockIdx.x * SCAN_B + threadIdx.x;
    if (gid < n) pos[gid] += bsums[blockIdx.x];
}

// XCD-partitioned CSR fill (verified R4).
__global__ __launch_bounds__(256) void csr_fill_xcd(const int* __restrict__ src,
                                                    const int* __restrict__ dst,
                                                    int* __restrict__ pos,
                                                    int* __restrict__ csr_src, int E) {
    int g = blockIdx.x & 7;
    int sub = blockIdx.x >> 3;
    int nsub = gridDim.x >> 3;
    int lo = g * (NNODES / 8), hi = lo + (NNODES / 8);
    for (int e = sub * 256 + threadIdx.x; e < E; e += nsub * 256) {
        int d = dst[e];
        if (d >= lo && d < hi) {
            int slot = atomicAdd(&pos[d], 1);
            csr_src[slot] = src[e];
        }
    }
}

// ---------------- weight convert: fragment-contiguous layouts ----------------
// W1f: for k-tile t (16), col-group j (8), lane l (64): 8 bf16 at
//   W1f[((t*8+j)*64+l)*8 + jj] = bf16(W1[k][n]), k = t*32+(l>>4)*8+jj, n = j*16+(l&15)

__global__ __launch_bounds__(256) void conv_w1f(const float* __restrict__ W1,
                                                unsigned short* __restrict__ W1f) {
    int idx = blockIdx.x * 256 + threadIdx.x;    // 16*8*64 = 8192
    if (idx >= 8192) return;
    int t = idx >> 9;
    int rest = idx & 511;
    int j = rest >> 6;
    int l = rest & 63;
    int n = j * 16 + (l & 15);
    int kb = t * 32 + (l >> 4) * 8;
    bf16x8 o;
    #pragma unroll
    for (int jj = 0; jj < 8; jj++) {
        int k = kb + jj;
        o[jj] = (k < 500) ? (short)f2bf(W1[k * 128 + n]) : (short)0;
    }
    *(bf16x8*)(W1f + (size_t)idx * 8) = o;
}

// W2f: k-tiles t (4), col-groups j (4), lanes l (64); k = t*32+(l>>4)*8+jj, n = j*16+(l&15)
__global__ __launch_bounds__(256) void conv_w2f(const float* __restrict__ W2,
                                                unsigned short* __restrict__ W2f) {
    int idx = blockIdx.x * 256 + threadIdx.x;    // 4*4*64 = 1024
    if (idx >= 1024) return;
    int t = idx >> 8;
    int rest = idx & 255;
    int j = rest >> 6;
    int l = rest & 63;
    int n = j * 16 + (l & 15);
    int kb = t * 32 + (l >> 4) * 8;
    bf16x8 o;
    #pragma unroll
    for (int jj = 0; jj < 8; jj++)
        o[jj] = (short)f2bf(W2[(kb + jj) * 64 + n]);
    *(bf16x8*)(W2f + (size_t)idx * 8) = o;
}

// ---------------- layer-1 MFMA GEMM: h1'[M,128](bf16) = dinv .* (x @ W1) ----------
// BM=64, 2-phase async pipeline via global_load_lds (register-free staging the
// compiler cannot sink): STAGE(buf^1, t+1) issues async DMA, then COMPUTE(buf, t)
// runs ds_read+cvt+MFMA while the DMA flies; vmcnt(0)+barrier once per iter.
// B (wave-invariant) staged by wave 0 only; each wave stages its own A rows.
// Tile 15 (K tail) via guarded register loads issued at t=14.

__global__ __launch_bounds__(256) void gemm1_mfma(
    const float* __restrict__ x, const unsigned short* __restrict__ W1f,
    const float* __restrict__ dinv, unsigned short* __restrict__ C, int M)
{
    __shared__ float sA[2][2048];            // [buf][w*512 + chunk*256 + l*4], 8KB/buf
    __shared__ unsigned short sB[2][4096];   // [buf][j*512 + l*8], 8KB/buf
    const int tid = threadIdx.x;
    const int w = tid >> 6;
    const int l = tid & 63;
    const int lm = l & 15;
    const int q = l >> 4;
    const int l4 = l * 4;
    const int row0 = blockIdx.x * 64;

    int r = row0 + w * 16 + lm;
    if (r >= M) r = M - 1;
    const float* abase = x + (size_t)r * 500 + q * 8;

    f32x4 acc[8];
    #pragma unroll
    for (int j = 0; j < 8; j++) acc[j] = (f32x4){0.f, 0.f, 0.f, 0.f};

    // stage tile t (t <= 14: all addresses in-bounds, max elem 448+24+7=479<500)
    auto STAGE = [&](int buf, int t) {
        const float* g0 = abase + t * 32;
        gload16(g0,     &sA[buf][w * 512 + 0]);
        gload16(g0 + 4, &sA[buf][w * 512 + 256]);
        if (w == 0) {
            #pragma unroll
            for (int j = 0; j < 8; j++)
                gload16(W1f + (((size_t)t * 8 + j) * 64 + l) * 8, &sB[buf][j * 512]);
        }
    };

    STAGE(0, 0);
    asm volatile("s_waitcnt vmcnt(0)" ::: "memory");
    __syncthreads();

    bf16x8 a15;
    bf16x8 b15[8];
    int buf = 0;
    for (int t = 0; t < 15; ++t) {
        if (t < 14) {
            STAGE(buf ^ 1, t + 1);
        } else {
            // tile 15 -> registers (guarded tail), flies under compute of t=14
            bf16x8 o;
            #pragma unroll
            for (int jj = 0; jj < 8; jj++) {
                int k = 480 + q * 8 + jj;
                o[jj] = (k < 500) ? (short)f2bf(abase[480 + jj]) : (short)0;
            }
            a15 = o;
            #pragma unroll
            for (int j = 0; j < 8; j++)
                b15[j] = *(const bf16x8*)(W1f + (((size_t)15 * 8 + j) * 64 + l) * 8);
        }
        // compute tile t from LDS[buf]
        float4 u = *(const float4*)&sA[buf][w * 512 + l4];
        float4 v = *(const float4*)&sA[buf][w * 512 + 256 + l4];
        bf16x8 af;
        af[0] = f2bf(u.x); af[1] = f2bf(u.y); af[2] = f2bf(u.z); af[3] = f2bf(u.w);
        af[4] = f2bf(v.x); af[5] = f2bf(v.y); af[6] = f2bf(v.z); af[7] = f2bf(v.w);
        #pragma unroll
        for (int j = 0; j < 8; j++) {
            bf16x8 bfr = *(const bf16x8*)&sB[buf][j * 512 + l * 8];
            acc[j] = __builtin_amdgcn_mfma_f32_16x16x32_bf16(af, bfr, acc[j], 0, 0, 0);
        }
        asm volatile("s_waitcnt vmcnt(0)" ::: "memory");
        __syncthreads();
        buf ^= 1;
    }
    // tile 15 from registers
    #pragma unroll
    for (int j = 0; j < 8; j++)
        acc[j] = __builtin_amdgcn_mfma_f32_16x16x32_bf16(a15, b15[j], acc[j], 0, 0, 0);

    // C/D layout: col = j*16 + lm, row = q*4 + reg (+ w*16); pre-scale by dinv[row]
    #pragma unroll
    for (int reg = 0; reg < 4; reg++) {
        int grow = row0 + w * 16 + q * 4 + reg;
        if (grow < M) {
            float d = dinv[grow];
            #pragma unroll
            for (int j = 0; j < 8; j++)
                C[(size_t)grow * 128 + j * 16 + lm] = f2bf(d * acc[j][reg]);
        }
    }
}

// ---------------- layer-2 MFMA GEMM: h2'[M,64](bf16) = dinv .* (a1 @ W2) ----------
// Barrier-free register-direct (verified R7).

__global__ __launch_bounds__(256) void gemm2_mfma(
    const unsigned short* __restrict__ A, const unsigned short* __restrict__ W2f,
    const float* __restrict__ dinv, unsigned short* __restrict__ C, int M)
{
    const int tid = threadIdx.x;
    const int w = tid >> 6;
    const int l = tid & 63;
    const int lm = l & 15;
    const int q = l >> 4;
    const int row0 = blockIdx.x * 128;

    const unsigned short* abase[2];
    #pragma unroll
    for (int i = 0; i < 2; i++) {
        int r = row0 + w * 32 + i * 16 + lm;
        if (r >= M) r = M - 1;
        abase[i] = A + (size_t)r * 128 + q * 8;
    }

    f32x4 acc[2][4];
    #pragma unroll
    for (int i = 0; i < 2; i++)
        #pragma unroll
        for (int j = 0; j < 4; j++) acc[i][j] = (f32x4){0.f, 0.f, 0.f, 0.f};

    for (int t = 0; t < 4; ++t) {
        const int k0 = t * 32;
        bf16x8 af[2];
        #pragma unroll
        for (int i = 0; i < 2; i++)
            af[i] = *(const bf16x8*)(abase[i] + k0);
        bf16x8 bfr[4];
        #pragma unroll
        for (int j = 0; j < 4; j++)
            bfr[j] = *(const bf16x8*)(W2f + (((size_t)t * 4 + j) * 64 + l) * 8);
        #pragma unroll
        for (int i = 0; i < 2; i++)
            #pragma unroll
            for (int j = 0; j < 4; j++)
                acc[i][j] = __builtin_amdgcn_mfma_f32_16x16x32_bf16(af[i], bfr[j], acc[i][j], 0, 0, 0);
    }

    #pragma unroll
    for (int i = 0; i < 2; i++) {
        #pragma unroll
        for (int reg = 0; reg < 4; reg++) {
            int grow = row0 + w * 32 + i * 16 + q * 4 + reg;
            if (grow < M) {
                float d = dinv[grow];
                #pragma unroll
                for (int j = 0; j < 4; j++)
                    C[(size_t)grow * 64 + j * 16 + lm] = f2bf(d * acc[i][j][reg]);
            }
        }
    }
}

// ---------------- layer-3 GEMM: h3'[M,40](fp32) = dinv .* (relu(A+b2) @ W4) ----------------

__global__ __launch_bounds__(256) void gemm_n40(
    const float* __restrict__ A, const float* __restrict__ W,
    const float* __restrict__ bias, const float* __restrict__ dinv,
    float* __restrict__ C, int M)
{
    __shared__ float sA[32][65];
    __shared__ float sW[64][40];
    const int row0 = blockIdx.x * 32;
    for (int idx = threadIdx.x; idx < 64 * 40; idx += 256)
        sW[idx / 40][idx % 40] = W[idx];
    for (int idx = threadIdx.x; idx < 32 * 64; idx += 256) {
        int r = idx >> 6, k = idx & 63;
        int row = row0 + r;
        float v = 0.0f;
        if (row < M) v = fmaxf(A[(long)row * 64 + k] + bias[k], 0.0f);
        sA[r][k] = v;
    }
    __syncthreads();
    float acc[5] = {0, 0, 0, 0, 0};
    int rr[5], cc[5];
    #pragma unroll
    for (int j = 0; j < 5; j++) {
        int o = threadIdx.x + 256 * j;
        rr[j] = o / 40; cc[j] = o % 40;
    }
    for (int k = 0; k < 64; k++) {
        #pragma unroll
        for (int j = 0; j < 5; j++) acc[j] += sA[rr[j]][k] * sW[k][cc[j]];
    }
    #pragma unroll
    for (int j = 0; j < 5; j++) {
        int row = row0 + rr[j];
        if (row < M) C[(long)row * 40 + cc[j]] = dinv[row] * acc[j];
    }
}

// ---------------- CSR gather over pre-scaled bf16 h': out[i] = di*(h'[i] + sum h'[s]) ----
// optional fused +bias,relu,->bf16 epilogue

template<int F, bool OBF16>
__global__ __launch_bounds__(256) void gather_bf(
    const unsigned short* __restrict__ h, const float* __restrict__ dinv,
    const int* __restrict__ pos, const int* __restrict__ csr_src,
    void* __restrict__ outv, const float* __restrict__ bias, int n)
{
    constexpr int P = F / 2;
    unsigned t = blockIdx.x * 256u + threadIdx.x;
    unsigned node = t / P;
    unsigned p = t - node * P;
    if (node >= (unsigned)n) return;
    int e0 = node ? pos[node - 1] : 0;
    int e1 = pos[node];
    float di = dinv[node];
    unsigned sv = *(const unsigned*)(h + (size_t)node * F + 2 * p);
    float a0 = bflo(sv);
    float a1 = bfhi(sv);
    int j = e0;
    for (; j + 4 <= e1; j += 4) {
        int s0 = csr_src[j], s1 = csr_src[j + 1], s2 = csr_src[j + 2], s3 = csr_src[j + 3];
        unsigned v0 = *(const unsigned*)(h + (size_t)s0 * F + 2 * p);
        unsigned v1 = *(const unsigned*)(h + (size_t)s1 * F + 2 * p);
        unsigned v2 = *(const unsigned*)(h + (size_t)s2 * F + 2 * p);
        unsigned v3 = *(const unsigned*)(h + (size_t)s3 * F + 2 * p);
        a0 += bflo(v0) + bflo(v1) + bflo(v2) + bflo(v3);
        a1 += bfhi(v0) + bfhi(v1) + bfhi(v2) + bfhi(v3);
    }
    for (; j < e1; j++) {
        int s = csr_src[j];
        unsigned v = *(const unsigned*)(h + (size_t)s * F + 2 * p);
        a0 += bflo(v);
        a1 += bfhi(v);
    }
    a0 *= di; a1 *= di;
    if constexpr (OBF16) {
        a0 = fmaxf(a0 + bias[2 * p], 0.0f);
        a1 = fmaxf(a1 + bias[2 * p + 1], 0.0f);
        ((unsigned*)outv)[(size_t)node * P + p] =
            ((unsigned)f2bf(a1) << 16) | (unsigned)f2bf(a0);
    } else {
        float2 r; r.x = a0; r.y = a1;
        ((float2*)outv)[(size_t)node * P + p] = r;
    }
}

// ---------------- fp32 CSR gather over pre-scaled h' (layer 3, F=40) ----------------

template<int F>
__global__ __launch_bounds__(256) void gather_agg(
    const float* __restrict__ h, const float* __restrict__ dinv,
    const int* __restrict__ pos, const int* __restrict__ csr_src,
    float* __restrict__ out, int n)
{
    unsigned t = blockIdx.x * 256u + threadIdx.x;
    unsigned node = t / F;
    unsigned c = t - node * F;
    if (node >= (unsigned)n) return;
    int e0 = node ? pos[node - 1] : 0;
    int e1 = pos[node];
    float di = dinv[node];
    float acc = h[(size_t)node * F + c];
    int j = e0;
    for (; j + 4 <= e1; j += 4) {
        int s0 = csr_src[j], s1 = csr_src[j + 1], s2 = csr_src[j + 2], s3 = csr_src[j + 3];
        float v0 = h[(size_t)s0 * F + c];
        float v1 = h[(size_t)s1 * F + c];
        float v2 = h[(size_t)s2 * F + c];
        float v3 = h[(size_t)s3 * F + c];
        acc += v0 + v1 + v2 + v3;
    }
    for (; j < e1; j++) {
        int s = csr_src[j];
        acc += h[(size_t)s * F + c];
    }
    out[(size_t)node * F + c] = di * acc;
}

// ---------------- log_softmax over rows of 40 (one wave per row), in-place safe ----------------

__global__ __launch_bounds__(256) void logsoftmax40(const float* __restrict__ h,
                                                    const float* __restrict__ bias,
                                                    float* __restrict__ out, int n) {
    int wave = (blockIdx.x * 256 + threadIdx.x) >> 6;
    int lane = threadIdx.x & 63;
    if (wave >= n) return;
    float x = 0.0f, v = -INFINITY;
    if (lane < 40) { x = h[(long)wave * 40 + lane] + bias[lane]; v = x; }
    #pragma unroll
    for (int off = 32; off; off >>= 1) v = fmaxf(v, __shfl_xor(v, off, 64));
    float ex = (lane < 40) ? expf(x - v) : 0.0f;
    float s = ex;
    #pragma unroll
    for (int off = 32; off; off >>= 1) s += __shfl_xor(s, off, 64);
    if (lane < 40) out[(long)wave * 40 + lane] = x - v - logf(s);
}

// ---------------- launch ----------------

extern "C" void kernel_launch(void* const* d_in, const int* in_sizes, int n_in,
                              void* d_out, int out_size, void* d_ws, size_t ws_size,
                              hipStream_t stream) {
    const float* x  = (const float*)d_in[0];
    const int*   ei = (const int*)d_in[1];
    const float* W1 = (const float*)d_in[2];
    const float* b1 = (const float*)d_in[3];
    const float* W2 = (const float*)d_in[4];
    const float* b2 = (const float*)d_in[5];
    const float* W4 = (const float*)d_in[6];
    const float* b4 = (const float*)d_in[7];
    float* out = (float*)d_out;
    float* ws  = (float*)d_ws;

    const int N = NNODES, E = NEDGES;
    const int* src = ei;
    const int* dst = ei + E;

    // workspace layout (float offsets), with overlay reuse (~85 MB total):
    float*          dinv    = ws;                              // 100k
    int*            deg     = (int*)(ws + 100000);
    int*            pos     = (int*)(ws + 200000);
    int*            bsums   = (int*)(ws + 300000);
    int*            csr_src = (int*)(ws + 300200);             // 1.6M ints
    unsigned short* W1f     = (unsigned short*)(ws + 1900200); // 65536 shorts
    unsigned short* W2f     = (unsigned short*)(ws + 1933000); // 8192 shorts
    // region R1: h1' bf16 [N][128]; later h2' bf16 [N][64]
    unsigned short* h1      = (unsigned short*)(ws + 1937100);
    unsigned short* h2      = (unsigned short*)(ws + 1937100);
    // region R2: a1 bf16 [N][128]; later h3' fp32 [N][40]
    unsigned short* a1      = (unsigned short*)(ws + 8337100);
    float*          h3      = ws + 8337100;
    // region R3: a2 fp32 [N][64]
    float*          a2      = ws + 14737100;
    float*          a3      = out;

    const int nscan = (N + SCAN_B - 1) / SCAN_B;

    // ---- CSR build + norm ----
    zero_deg<<<(N + 255) / 256, 256, 0, stream>>>(deg, N);
    count_deg_xcd<<<1024, 256, 0, stream>>>(dst, deg, E);
    calc_dinv<<<(N + 255) / 256, 256, 0, stream>>>(deg, dinv, N);
    scan_block<<<nscan, SCAN_B, 0, stream>>>(deg, pos, bsums, N);
    scan_sums<<<1, 128, 0, stream>>>(bsums, nscan);
    add_off<<<nscan, SCAN_B, 0, stream>>>(pos, bsums, N);
    csr_fill_xcd<<<1024, 256, 0, stream>>>(src, dst, pos, csr_src, E);

    // ---- weights convert (fragment layouts) ----
    conv_w1f<<<32, 256, 0, stream>>>(W1, W1f);
    conv_w2f<<<4, 256, 0, stream>>>(W2, W2f);

    // ---- layer 1: h1' = dinv.*(x @ W1) ; a1(bf16) = relu(di*(h1'[i]+sum h1'[s]) + b1) ----
    gemm1_mfma<<<(N + 63) / 64, 256, 0, stream>>>(x, W1f, dinv, h1, N);
    {
        unsigned tot = (unsigned)N * 64u;
        gather_bf<128, true><<<(tot + 255) / 256, 256, 0, stream>>>(h1, dinv, pos, csr_src, a1, b1, N);
    }

    // ---- layer 2: h2' = dinv.*(a1 @ W2) ; a2(fp32) = di*(h2'[i]+sum h2'[s]) ----
    gemm2_mfma<<<(N + 127) / 128, 256, 0, stream>>>(a1, W2f, dinv, h2, N);
    {
        unsigned tot = (unsigned)N * 32u;
        gather_bf<64, false><<<(tot + 255) / 256, 256, 0, stream>>>(h2, dinv, pos, csr_src, a2, nullptr, N);
    }

    // ---- layer 3: h3' = dinv.*(relu(a2+b2) @ W4) ; a3 = di*(h3'[i]+sum h3'[s]) ----
    gemm_n40<<<(N + 31) / 32, 256, 0, stream>>>(a2, W4, b2, dinv, h3, N);
    {
        unsigned tot = (unsigned)N * 40u;
        gather_agg<40><<<(tot + 255) / 256, 256, 0, stream>>>(h3, dinv, pos, csr_src, a3, N);
    }

    // ---- log_softmax(a3 + b4) in place ----
    logsoftmax40<<<(N * 64 + 255) / 256, 256, 0, stream>>>(a3, b4, out, N);
}